// Round 9
// baseline (270.298 us; speedup 1.0000x reference)
//
#include <hip/hip_runtime.h>
#include <math.h>

// Problem constants (fixed shapes per reference)
constexpr int NPB = 15;   // NUM_PROB_BINS
constexpr int NC  = 8;    // NUM_CLASSES
constexpr int NNB = 9;    // NUM_NEIGHBOR_CLASSES (3x3)
constexpr int Bn  = 16;
constexpr int Hc  = 512;
constexpr int Wc  = 512;

// Tile: 64x32 outputs, +1 halo ring. A block PERSISTS over 4 adjacent
// tiles (a 256x32 band): grid = 512 blocks = exactly 2/CU resident in a
// single residency wave (no launch rounds). Cross-tile pipelining: tile
// j+1's global loads are issued before phase-2(j) and retire under its
// LDS reads + math.
constexpr int TX = 64, TY = 32;
constexpr int HX = TX + 2;  // 66
constexpr int HY = TY + 2;  // 34
constexpr int NT = 1024;
constexpr int TPB = 4;                 // tiles per block, along x
constexpr int NBLK = 512;              // 16 img * 16 by * 2 halves
constexpr int NHALO = HX * HY;         // 2244

typedef float f32x2 __attribute__((ext_vector_type(2)));

// 4-wide step-interleaved fp32-correctly-rounded exp (d in [-90,0]).
// PER-CLASS OP SEQUENCE IS BIT-IDENTICAL to the validated exp_f32_cr.
// 4-wide is the proven sweet spot (R6): 8-wide exceeds what the allocator
// will hold (R8: VGPR pinned 32, re-serialized, +4 us). NUMERICS FROZEN.
__device__ __forceinline__ void exp4_cr(const float* a, float* o) {
    double r[4], p[4];
    int    k[4];
    #pragma unroll
    for (int j = 0; j < 4; j++) {
        const double d = (double)a[j];
        double kd = rint(d * 2.8853900817779268);      // 2*log2(e)
        k[j] = (int)kd;
        r[j] = fma(kd, -0.34657359027997265, d);       // nearest-double -(ln2/2)
        p[j] = 2.48015873015873016e-5;                 // 1/8!
    }
    #pragma unroll
    for (int j = 0; j < 4; j++) p[j] = fma(p[j], r[j], 1.98412698412698413e-4);
    #pragma unroll
    for (int j = 0; j < 4; j++) p[j] = fma(p[j], r[j], 1.38888888888888889e-3);
    #pragma unroll
    for (int j = 0; j < 4; j++) p[j] = fma(p[j], r[j], 8.33333333333333333e-3);
    #pragma unroll
    for (int j = 0; j < 4; j++) p[j] = fma(p[j], r[j], 4.16666666666666666e-2);
    #pragma unroll
    for (int j = 0; j < 4; j++) p[j] = fma(p[j], r[j], 1.66666666666666667e-1);
    #pragma unroll
    for (int j = 0; j < 4; j++) p[j] = fma(p[j], r[j], 0.5);
    #pragma unroll
    for (int j = 0; j < 4; j++) p[j] = fma(p[j], r[j], 1.0);
    #pragma unroll
    for (int j = 0; j < 4; j++) p[j] = fma(p[j], r[j], 1.0);
    #pragma unroll
    for (int j = 0; j < 4; j++) {
        double v = (k[j] & 1) ? p[j] * 1.4142135623730951 : p[j];
        long long bits = __double_as_longlong(v) + ((long long)(k[j] >> 1) << 52);
        o[j] = (float)__longlong_as_double(bits);
    }
}

// Reciprocal to ~1 ulp of double: rcp_f32 seed + 2 fp64 Newton iters.
// NUMERICS FROZEN.
__device__ __forceinline__ double rcp64(float s) {
    double dS = (double)s;
    double r  = (double)__builtin_amdgcn_rcpf(s);
    r = r * fma(-dS, r, 2.0);
    r = r * fma(-dS, r, 2.0);
    return r;
}

__global__ __launch_bounds__(NT, 8)  // 8 waves/EU -> 2 blocks/CU, VGPR cap 64
void nectar_kernel(const float* __restrict__ logits,
                   const float* __restrict__ vf,
                   float* __restrict__ out)
{
    __shared__ __align__(16) float sP[NC][HY][HX];  // halo softmax probs: 71808 B
    __shared__ float sVF[NC * NNB * NPB];           // calibration table:   4320 B
    // total 76128 B -> 2 blocks/CU, 32 waves/CU

    const int tid = threadIdx.x;

    // Bijective XCD swizzle (512 % 8 == 0): hw round-robins blockIdx over
    // 8 XCDs; remap so XCD k owns sem [64k, 64k+64) = 2 whole images'
    // worth of bands -> all halo/cache-line re-reads hit that XCD's L2.
    const int h   = blockIdx.x;             // 0..511
    const int sem = (h & 7) * 64 + (h >> 3);
    const int b   = sem >> 5;               // image 0..15
    const int rr  = sem & 31;
    const int by  = rr >> 1;                // 0..15
    const int g   = rr & 1;                 // band half 0..1
    const int y0  = by * TY;

    const size_t plane = (size_t)Hc * Wc;
    const float* src = logits + (size_t)b * NC * plane;

    // Stage the calibration table (1080 floats > NT -> strided).
    for (int i = tid; i < NC * NNB * NPB; i += NT) sVF[i] = vf[i];

    // ---- Tile-invariant phase-1 task geometry. Task t covers halo pixel
    // (ly,lx) = ((tid+t*NT)/66, (tid+t*NT)%66); only gx depends on the
    // tile's x0. t=2 valid only for tid < 196.
    int ly_[3], lx_[3];
    unsigned rowo_[3];                      // clamped gy * Wc
    bool imy_[3];
    const bool has2 = tid < (NHALO - 2 * NT);   // tid < 196
    #pragma unroll
    for (int t = 0; t < 3; t++) {
        const int i  = tid + t * NT;
        const int ly = (int)((unsigned)i / (unsigned)HX);
        const int lx = i - ly * HX;
        const int gy = y0 + ly - 1;
        ly_[t]  = ly;
        lx_[t]  = lx;
        imy_[t] = (unsigned)gy < (unsigned)Hc;
        const int gyc = gy < 0 ? 0 : (gy > Hc - 1 ? Hc - 1 : gy);
        rowo_[t] = (unsigned)(gyc * Wc);
    }

    // Tile-invariant phase-2 geometry: 2 horizontally adjacent outputs.
    const int lx2 = (tid & 31) * 2;         // 0,2,..,62
    const int oy  = tid >> 5;               // 0..31
    const unsigned rowout = (unsigned)((y0 + oy) * Wc);
    const double C9 = 0.1111111111111111111;    // nearest double to 1/9

    // Per-tile voffset/validity for task t at tile origin x0.
    auto task_off = [&](int t, int x0, bool& im) -> unsigned {
        const int gx  = x0 + lx_[t] - 1;
        const int gxc = gx < 0 ? 0 : (gx > Wc - 1 ? Wc - 1 : gx);
        im = imy_[t] && ((unsigned)gx < (unsigned)Wc);
        return rowo_[t] + (unsigned)gxc;
    };

    const int x0base = g * (TX * TPB);      // 0 or 256

    // Prefetch tile 0, tasks 0/1 (SGPR class base + 32-bit lane offset).
    float v0[NC], v1[NC];
    bool  im0, im1;
    {
        const unsigned voa = task_off(0, x0base, im0);
        const unsigned vob = task_off(1, x0base, im1);
        #pragma unroll
        for (int c = 0; c < NC; c++) {
            const float* bc = src + (size_t)c * plane;
            v0[c] = bc[voa];
            v1[c] = bc[vob];
        }
    }

    for (int j = 0; j < TPB; ++j) {
        const int xj = x0base + j * TX;

        // ---- Phase 1, tile j. Per-task fp32/fp64 op ORDER byte-identical
        // to the validated pipeline. OOB -> rS=0.0 -> exact +0.0 products.
        {   // Task 0 (from prefetched v0)
            float m = v0[0];
            #pragma unroll
            for (int c = 1; c < NC; c++) m = fmaxf(m, v0[c]);
            float d[NC], e[NC];
            #pragma unroll
            for (int c = 0; c < NC; c++) d[c] = v0[c] - m;
            exp4_cr(d, e);
            exp4_cr(d + 4, e + 4);
            float S = 0.0f;
            #pragma unroll
            for (int c = 0; c < NC; c++) S = S + e[c];   // sequential (order sacred)
            double rS = rcp64(S);
            rS = im0 ? rS : 0.0;
            #pragma unroll
            for (int c = 0; c < NC; c++)
                sP[c][ly_[0]][lx_[0]] = (float)((double)e[c] * rS);
        }

        // Task-2 loads retire under task-1's softmax.
        float v2[NC];
        bool  im2 = false;
        if (has2) {
            const unsigned voc = task_off(2, xj, im2);
            #pragma unroll
            for (int c = 0; c < NC; c++) v2[c] = (src + (size_t)c * plane)[voc];
        }

        {   // Task 1 (from prefetched v1)
            float m = v1[0];
            #pragma unroll
            for (int c = 1; c < NC; c++) m = fmaxf(m, v1[c]);
            float d[NC], e[NC];
            #pragma unroll
            for (int c = 0; c < NC; c++) d[c] = v1[c] - m;
            exp4_cr(d, e);
            exp4_cr(d + 4, e + 4);
            float S = 0.0f;
            #pragma unroll
            for (int c = 0; c < NC; c++) S = S + e[c];
            double rS = rcp64(S);
            rS = im1 ? rS : 0.0;
            #pragma unroll
            for (int c = 0; c < NC; c++)
                sP[c][ly_[1]][lx_[1]] = (float)((double)e[c] * rS);
        }

        if (has2) {   // Task 2
            float m = v2[0];
            #pragma unroll
            for (int c = 1; c < NC; c++) m = fmaxf(m, v2[c]);
            float d[NC], e[NC];
            #pragma unroll
            for (int c = 0; c < NC; c++) d[c] = v2[c] - m;
            exp4_cr(d, e);
            exp4_cr(d + 4, e + 4);
            float S = 0.0f;
            #pragma unroll
            for (int c = 0; c < NC; c++) S = S + e[c];
            double rS = rcp64(S);
            rS = im2 ? rS : 0.0;
            #pragma unroll
            for (int c = 0; c < NC; c++)
                sP[c][ly_[2]][lx_[2]] = (float)((double)e[c] * rS);
        }
        __syncthreads();

        // ---- Cross-tile pipeline: issue tile j+1's task-0/1 loads NOW.
        // They retire under phase-2's LDS reads + math; the end-of-iter
        // barrier's vmcnt drain lands after that overlap window.
        if (j + 1 < TPB) {
            const unsigned voa = task_off(0, xj + TX, im0);
            const unsigned vob = task_off(1, xj + TX, im1);
            #pragma unroll
            for (int c = 0; c < NC; c++) {
                const float* bc = src + (size_t)c * plane;
                v0[c] = bc[voa];
                v1[c] = bc[vob];
            }
        }

        // ---- Phase 2, tile j: 2 adjacent outputs per thread. lx2 even +
        // row stride 66 (even) -> all window reads 8B-aligned ds_read_b64.
        float calL[NC], calR[NC];
        float s0 = 0.0f, s1 = 0.0f;
        #pragma unroll
        for (int c = 0; c < NC; c++) {
            const float* base = &sP[c][oy][lx2];
            f32x2 u0 = *(const f32x2*)(base);
            f32x2 w0 = *(const f32x2*)(base + 2);
            f32x2 u1 = *(const f32x2*)(base + HX);
            f32x2 w1 = *(const f32x2*)(base + HX + 2);
            f32x2 u2 = *(const f32x2*)(base + 2 * HX);
            f32x2 w2 = *(const f32x2*)(base + 2 * HX + 2);
            // Strict left-to-right sequential add chains (row-major (dy,dx)
            // order) — reassociation would flip bins, order is sacred.
            float a0 = ((((((((u0.x + u0.y) + w0.x) + u1.x) + u1.y) + w1.x) + u2.x) + u2.y) + w2.x);
            float a1 = ((((((((u0.y + w0.x) + w0.y) + u1.y) + w1.x) + w1.y) + u2.y) + w2.x) + w2.y);

            float nm0 = (float)((double)a0 * C9);   // fl32(a/9) via double mul
            float nm1 = (float)((double)a1 * C9);
            int lb0 = (int)(nm0 * 9.0f);            // trunc == floor (nm >= 0)
            int lb1 = (int)(nm1 * 9.0f);
            lb0 = lb0 > NNB - 1 ? NNB - 1 : lb0;
            lb1 = lb1 > NNB - 1 ? NNB - 1 : lb1;
            int pb0 = (int)(u1.y * 15.0f);          // center of left window
            int pb1 = (int)(w1.x * 15.0f);          // center of right window
            pb0 = pb0 > NPB - 1 ? NPB - 1 : pb0;
            pb1 = pb1 > NPB - 1 ? NPB - 1 : pb1;
            calL[c] = sVF[(c * NNB + lb0) * NPB + pb0];
            calR[c] = sVF[(c * NNB + lb1) * NPB + pb1];
            s0 = s0 + calL[c];                      // sequential class sum
            s1 = s1 + calR[c];
        }
        if (s0 == 0.0f) s0 = 1.0f;
        if (s1 == 0.0f) s1 = 1.0f;

        // Final normalize is NOT bin-critical: fp32 rcp + 1 Newton.
        float q0 = __builtin_amdgcn_rcpf(s0);
        q0 = q0 * fmaf(-s0, q0, 2.0f);
        float q1 = __builtin_amdgcn_rcpf(s1);
        q1 = q1 * fmaf(-s1, q1, 2.0f);

        // Nontemporal dwordx2 stores (write-once output; don't evict the
        // L3-resident logits). SGPR class base + 32-bit voffset.
        const unsigned voff_out = rowout + (unsigned)(xj + lx2);
        #pragma unroll
        for (int c = 0; c < NC; c++) {
            float* oc = out + ((size_t)b * NC + (size_t)c) * plane;
            f32x2 o;
            o.x = calL[c] * q0;
            o.y = calR[c] * q1;
            __builtin_nontemporal_store(o, (f32x2*)(oc + voff_out));
        }
        __syncthreads();   // protect sP before tile j+1's phase-1 writes
    }
}

extern "C" void kernel_launch(void* const* d_in, const int* in_sizes, int n_in,
                              void* d_out, int out_size, void* d_ws, size_t ws_size,
                              hipStream_t stream) {
    const float* logits = (const float*)d_in[0];
    const float* vf     = (const float*)d_in[1];
    float* out          = (float*)d_out;

    nectar_kernel<<<dim3(NBLK), dim3(NT), 0, stream>>>(logits, vf, out);
}